// Round 2
// baseline (222.949 us; speedup 1.0000x reference)
//
#include <hip/hip_runtime.h>

namespace {

constexpr int T = 5, F = 30, H = 20;
constexpr int BATCH = 131072;

__device__ __forceinline__ float sig(float v) {
  return 1.0f / (1.0f + __expf(-v));
}

// NaN-safe fast tanh: e in (0,1], no inf/inf.
__device__ __forceinline__ float tanh_fast(float v) {
  float e = __expf(-2.0f * fabsf(v));
  float r = (1.0f - e) / (1.0f + e);
  return copysignf(r, v);
}

__global__ __launch_bounds__(256, 2) void lstm_fused(
    const float* __restrict__ x,
    const float* __restrict__ wf, const float* __restrict__ wi,
    const float* __restrict__ wo, const float* __restrict__ wc,
    const float* __restrict__ uf, const float* __restrict__ ui,
    const float* __restrict__ uo, const float* __restrict__ uc,
    const float* __restrict__ bf, const float* __restrict__ bi,
    const float* __restrict__ bo, const float* __restrict__ bc,
    float* __restrict__ out)
{
  const int b = blockIdx.x * blockDim.x + threadIdx.x;
  if (b >= BATCH) return;

  const float* xb = x + (size_t)b * (T * F);
  float* ob = out + (size_t)b * (T * H);

  float h[H], c[H];
#pragma unroll
  for (int j = 0; j < H; ++j) { h[j] = 0.0f; c[j] = 0.0f; }

  for (int t = 0; t < T; ++t) {
    float gf[H], gi[H], go[H], gc[H];
#pragma unroll
    for (int j = 0; j < H; ++j) {
      gf[j] = bf[j]; gi[j] = bi[j]; go[j] = bo[j]; gc[j] = bc[j];
    }

    // Input projection: gx += x[b,t,:] @ W  (weights wave-uniform -> scalar loads)
    // x read straight from global (L1 line reuse across k); avoids a
    // runtime-indexed local array (scratch hazard).
    for (int k = 0; k < F; ++k) {
      float xv = xb[t * F + k];
#pragma unroll
      for (int j = 0; j < H; ++j) {
        gf[j] = fmaf(xv, wf[k * H + j], gf[j]);
        gi[j] = fmaf(xv, wi[k * H + j], gi[j]);
        go[j] = fmaf(xv, wo[k * H + j], go[j]);
        gc[j] = fmaf(xv, wc[k * H + j], gc[j]);
      }
    }

    // Recurrent: gx += h @ U. Fully unrolled so h[k] is a static register
    // index (rule #20). At t==0, h==0 -> identical to skipping the term.
#pragma unroll
    for (int k = 0; k < H; ++k) {
      float hv = h[k];
#pragma unroll
      for (int j = 0; j < H; ++j) {
        gf[j] = fmaf(hv, uf[k * H + j], gf[j]);
        gi[j] = fmaf(hv, ui[k * H + j], gi[j]);
        go[j] = fmaf(hv, uo[k * H + j], go[j]);
        gc[j] = fmaf(hv, uc[k * H + j], gc[j]);
      }
    }

    // Gates + state update
#pragma unroll
    for (int j = 0; j < H; ++j) {
      float fg = sig(gf[j]);
      float ig = sig(gi[j]);
      float og = sig(go[j]);
      float ch = tanh_fast(gc[j]);
      float cn = fmaf(fg, c[j], ig * ch);
      c[j] = cn;
      h[j] = og * tanh_fast(cn);
    }

    // Store h -> out[b,t,:], 5x float4 (alignment: b*400B and t*80B are 16B-mult)
    float4* op = (float4*)(ob + t * H);
#pragma unroll
    for (int q = 0; q < H / 4; ++q) {
      float4 v;
      v.x = h[4 * q + 0];
      v.y = h[4 * q + 1];
      v.z = h[4 * q + 2];
      v.w = h[4 * q + 3];
      op[q] = v;
    }
  }
}

} // namespace

extern "C" void kernel_launch(void* const* d_in, const int* in_sizes, int n_in,
                              void* d_out, int out_size, void* d_ws, size_t ws_size,
                              hipStream_t stream) {
  const float* x  = (const float*)d_in[0];
  const float* wf = (const float*)d_in[1];
  const float* wi = (const float*)d_in[2];
  const float* wo = (const float*)d_in[3];
  const float* wc = (const float*)d_in[4];
  const float* uf = (const float*)d_in[5];
  const float* ui = (const float*)d_in[6];
  const float* uo = (const float*)d_in[7];
  const float* uc = (const float*)d_in[8];
  const float* bf = (const float*)d_in[9];
  const float* bi = (const float*)d_in[10];
  const float* bo = (const float*)d_in[11];
  const float* bc = (const float*)d_in[12];
  float* out = (float*)d_out;

  dim3 block(256);
  dim3 grid((BATCH + 255) / 256);
  hipLaunchKernelGGL(lstm_fused, grid, block, 0, stream,
                     x, wf, wi, wo, wc, uf, ui, uo, uc, bf, bi, bo, bc, out);
}

// Round 3
// 164.064 us; speedup vs baseline: 1.3589x; 1.3589x over previous
//
#include <hip/hip_runtime.h>

namespace {

constexpr int T = 5, F = 30, H = 20;
constexpr int BATCH = 131072;
constexpr int BPB = 64;   // batch rows per block (one per lane)
constexpr int HP = 21;    // padded LDS row: odd dword stride -> 2-way bank aliasing (free)

__device__ __forceinline__ float sig(float v) { return 1.0f / (1.0f + __expf(-v)); }

// NaN-safe fast tanh: e in (0,1], no inf/inf.
__device__ __forceinline__ float tanh_fast(float v) {
  float e = __expf(-2.0f * fabsf(v));
  float r = (1.0f - e) / (1.0f + e);
  return copysignf(r, v);
}

__global__ __launch_bounds__(256, 6) void lstm_split(
    const float* __restrict__ x,
    const float* __restrict__ wf, const float* __restrict__ wi,
    const float* __restrict__ wo, const float* __restrict__ wc,
    const float* __restrict__ uf, const float* __restrict__ ui,
    const float* __restrict__ uo, const float* __restrict__ uc,
    const float* __restrict__ bf, const float* __restrict__ bi,
    const float* __restrict__ bo, const float* __restrict__ bc,
    float* __restrict__ out)
{
  const int lane = threadIdx.x & 63;
  const int wv   = threadIdx.x >> 6;     // wave id 0..3
  // j-offset owned by this wave. Value is wave-uniform; readfirstlane forces
  // the compiler's uniformity analysis to agree so weight loads stay s_load.
  const int jo = __builtin_amdgcn_readfirstlane(wv * 5);
  const int b  = blockIdx.x * BPB + lane;

  const float* xb = x + (size_t)b * (T * F);
  float*       ob = out + (size_t)b * (T * H) + jo;

  __shared__ float hbuf[2][BPB][HP];

  float c[5];
#pragma unroll
  for (int jj = 0; jj < 5; ++jj) c[jj] = 0.0f;

  int cur = 0;
  for (int t = 0; t < T; ++t) {
    // gate accumulators, bias-initialized (uniform -> scalar loads)
    float af[5], ai_[5], ao[5], ac[5];
#pragma unroll
    for (int jj = 0; jj < 5; ++jj) {
      af[jj]  = bf[jo + jj];
      ai_[jj] = bi[jo + jj];
      ao[jj]  = bo[jo + jj];
      ac[jj]  = bc[jo + jj];
    }

    // x row -> registers (float2: b*600B + t*120B is 8B-aligned)
    float xv[F];
    const float2* xr2 = (const float2*)(xb + t * F);
#pragma unroll
    for (int q = 0; q < F / 2; ++q) {
      float2 v = xr2[q];
      xv[2 * q]     = v.x;
      xv[2 * q + 1] = v.y;
    }

    // input projection: 30k x 5j x 4 gates (weights via scalar pipe)
#pragma unroll
    for (int k = 0; k < F; ++k) {
#pragma unroll
      for (int jj = 0; jj < 5; ++jj) {
        af[jj]  = fmaf(xv[k], wf[k * H + jo + jj], af[jj]);
        ai_[jj] = fmaf(xv[k], wi[k * H + jo + jj], ai_[jj]);
        ao[jj]  = fmaf(xv[k], wo[k * H + jo + jj], ao[jj]);
        ac[jj]  = fmaf(xv[k], wc[k * H + jo + jj], ac[jj]);
      }
    }

    // recurrent projection from LDS h of t-1 (t=0: h==0 -> skip, exactly the
    // reference's t=0 special case)
    if (t > 0) {
      const float* hrow = hbuf[cur][lane];
#pragma unroll
      for (int k = 0; k < H; ++k) {
        float hv = hrow[k];   // lanes stride 21 dwords -> 2-way banks, free
#pragma unroll
        for (int jj = 0; jj < 5; ++jj) {
          af[jj]  = fmaf(hv, uf[k * H + jo + jj], af[jj]);
          ai_[jj] = fmaf(hv, ui[k * H + jo + jj], ai_[jj]);
          ao[jj]  = fmaf(hv, uo[k * H + jo + jj], ao[jj]);
          ac[jj]  = fmaf(hv, uc[k * H + jo + jj], ac[jj]);
        }
      }
    }

    // gates + state update; publish h to LDS for all waves; write out
    float* hw = hbuf[cur ^ 1][lane] + jo;
#pragma unroll
    for (int jj = 0; jj < 5; ++jj) {
      float fg = sig(af[jj]);
      float ig = sig(ai_[jj]);
      float og = sig(ao[jj]);
      float ch = tanh_fast(ac[jj]);
      float cn = fmaf(fg, c[jj], ig * ch);
      c[jj] = cn;
      float hn = og * tanh_fast(cn);
      hw[jj] = hn;
      ob[t * H + jj] = hn;
    }

    __syncthreads();   // writes to hbuf[cur^1] visible before next t reads
    cur ^= 1;
  }
}

} // namespace

extern "C" void kernel_launch(void* const* d_in, const int* in_sizes, int n_in,
                              void* d_out, int out_size, void* d_ws, size_t ws_size,
                              hipStream_t stream) {
  const float* x  = (const float*)d_in[0];
  const float* wf = (const float*)d_in[1];
  const float* wi = (const float*)d_in[2];
  const float* wo = (const float*)d_in[3];
  const float* wc = (const float*)d_in[4];
  const float* uf = (const float*)d_in[5];
  const float* ui = (const float*)d_in[6];
  const float* uo = (const float*)d_in[7];
  const float* uc = (const float*)d_in[8];
  const float* bf = (const float*)d_in[9];
  const float* bi = (const float*)d_in[10];
  const float* bo = (const float*)d_in[11];
  const float* bc = (const float*)d_in[12];
  float* out = (float*)d_out;

  dim3 block(256);
  dim3 grid(BATCH / BPB);   // 2048 blocks
  hipLaunchKernelGGL(lstm_split, grid, block, 0, stream,
                     x, wf, wi, wo, wc, uf, ui, uo, uc, bf, bi, bo, bc, out);
}

// Round 4
// 151.436 us; speedup vs baseline: 1.4722x; 1.0834x over previous
//
#include <hip/hip_runtime.h>

namespace {

constexpr int T = 5, F = 30, H = 20;
constexpr int BATCH = 131072;
constexpr int BPB = 64;   // batch rows per block (one per lane)
constexpr int HP = 21;    // padded LDS row: odd dword stride -> 2-way bank aliasing (free)

typedef float f32x2 __attribute__((ext_vector_type(2)));

__device__ __forceinline__ f32x2 fma2(f32x2 a, f32x2 b, f32x2 c) {
  return __builtin_elementwise_fma(a, b, c);   // aims at v_pk_fma_f32
}

// sigmoid via raw exp2/rcp: v=+inf -> 1, v=-inf -> 0, no NaN paths.
__device__ __forceinline__ float sig(float v) {
  return __builtin_amdgcn_rcpf(1.0f + __builtin_amdgcn_exp2f(v * -1.44269504f));
}
// tanh(v) = 2*sigmoid(2v) - 1: mul, exp, add, rcp, fma. Saturates correctly.
__device__ __forceinline__ float tanh_s(float v) {
  return fmaf(2.0f,
              __builtin_amdgcn_rcpf(1.0f + __builtin_amdgcn_exp2f(v * -2.88539008f)),
              -1.0f);
}

__global__ __launch_bounds__(256, 6) void lstm_pk(
    const float* __restrict__ x,
    const float* __restrict__ wf, const float* __restrict__ wi,
    const float* __restrict__ wo, const float* __restrict__ wc,
    const float* __restrict__ uf, const float* __restrict__ ui,
    const float* __restrict__ uo, const float* __restrict__ uc,
    const float* __restrict__ bf, const float* __restrict__ bi,
    const float* __restrict__ bo, const float* __restrict__ bc,
    float* __restrict__ out)
{
  const int lane = threadIdx.x & 63;
  const int wv   = threadIdx.x >> 6;                      // 0..3
  const int jo   = __builtin_amdgcn_readfirstlane(wv * 5);
  const int odd  = __builtin_amdgcn_readfirstlane(wv & 1);
  // Even-aligned pair base (pairs at pb,pb+1 and pb+2,pb+3) + leftover scalar.
  const int pb = jo + odd;              // even -> 8B-aligned weight pair loads
  const int sj = odd ? jo : jo + 4;     // the unpaired column
  const int b  = blockIdx.x * BPB + lane;

  const float* xb = x + (size_t)b * (T * F);
  float*       ob = out + (size_t)b * (T * H);

  __shared__ float hbuf[2][BPB][HP];

  // Hoisted biases (uniform -> SGPRs)
  const f32x2 bF0 = *(const f32x2*)(bf + pb), bF1 = *(const f32x2*)(bf + pb + 2);
  const f32x2 bI0 = *(const f32x2*)(bi + pb), bI1 = *(const f32x2*)(bi + pb + 2);
  const f32x2 bO0 = *(const f32x2*)(bo + pb), bO1 = *(const f32x2*)(bo + pb + 2);
  const f32x2 bC0 = *(const f32x2*)(bc + pb), bC1 = *(const f32x2*)(bc + pb + 2);
  const float bFs = bf[sj], bIs = bi[sj], bOs = bo[sj], bCs = bc[sj];

  f32x2 c0 = {0.f, 0.f}, c1 = {0.f, 0.f};
  float cs = 0.f;

  int cur = 0;
  for (int t = 0; t < T; ++t) {
    f32x2 f0 = bF0, f1 = bF1;  float fs = bFs;
    f32x2 i0 = bI0, i1 = bI1;  float is = bIs;
    f32x2 o0 = bO0, o1 = bO1;  float os = bOs;
    f32x2 g0 = bC0, g1 = bC1;  float gs = bCs;

    // x row -> registers (float2: base is 8B-aligned)
    float xv[F];
    const float2* xr2 = (const float2*)(xb + t * F);
#pragma unroll
    for (int q = 0; q < F / 2; ++q) {
      float2 v = xr2[q];
      xv[2 * q]     = v.x;
      xv[2 * q + 1] = v.y;
    }

    // input projection: per k, per gate: 2 pk_fma + 1 fma
#pragma unroll
    for (int k = 0; k < F; ++k) {
      const float xk = xv[k];
      const f32x2 x2 = {xk, xk};
      const int r = k * H;
      f0 = fma2(x2, *(const f32x2*)(wf + r + pb),     f0);
      f1 = fma2(x2, *(const f32x2*)(wf + r + pb + 2), f1);
      fs = fmaf(xk, wf[r + sj], fs);
      i0 = fma2(x2, *(const f32x2*)(wi + r + pb),     i0);
      i1 = fma2(x2, *(const f32x2*)(wi + r + pb + 2), i1);
      is = fmaf(xk, wi[r + sj], is);
      o0 = fma2(x2, *(const f32x2*)(wo + r + pb),     o0);
      o1 = fma2(x2, *(const f32x2*)(wo + r + pb + 2), o1);
      os = fmaf(xk, wo[r + sj], os);
      g0 = fma2(x2, *(const f32x2*)(wc + r + pb),     g0);
      g1 = fma2(x2, *(const f32x2*)(wc + r + pb + 2), g1);
      gs = fmaf(xk, wc[r + sj], gs);
    }

    // recurrent projection from LDS h of t-1 (t=0: h==0, skip — matches ref)
    if (t > 0) {
      const float* hrow = hbuf[cur][lane];
#pragma unroll
      for (int k = 0; k < H; ++k) {
        const float hv = hrow[k];      // stride-21 rows: 2-way banks, free
        const f32x2 h2 = {hv, hv};
        const int r = k * H;
        f0 = fma2(h2, *(const f32x2*)(uf + r + pb),     f0);
        f1 = fma2(h2, *(const f32x2*)(uf + r + pb + 2), f1);
        fs = fmaf(hv, uf[r + sj], fs);
        i0 = fma2(h2, *(const f32x2*)(ui + r + pb),     i0);
        i1 = fma2(h2, *(const f32x2*)(ui + r + pb + 2), i1);
        is = fmaf(hv, ui[r + sj], is);
        o0 = fma2(h2, *(const f32x2*)(uo + r + pb),     o0);
        o1 = fma2(h2, *(const f32x2*)(uo + r + pb + 2), o1);
        os = fmaf(hv, uo[r + sj], os);
        g0 = fma2(h2, *(const f32x2*)(uc + r + pb),     g0);
        g1 = fma2(h2, *(const f32x2*)(uc + r + pb + 2), g1);
        gs = fmaf(hv, uc[r + sj], gs);
      }
    }

    // gates + state update + publish
    float* hw = hbuf[cur ^ 1][lane];
    float hq[5];
    {
      // pair 0: j = pb, pb+1
      float fg, ig, og, ch, cn;
#pragma unroll
      for (int e = 0; e < 2; ++e) {
        fg = sig(f0[e]); ig = sig(i0[e]); og = sig(o0[e]); ch = tanh_s(g0[e]);
        cn = fmaf(fg, c0[e], ig * ch);
        c0[e] = cn;
        hq[e] = og * tanh_s(cn);
      }
      // pair 1: j = pb+2, pb+3
#pragma unroll
      for (int e = 0; e < 2; ++e) {
        fg = sig(f1[e]); ig = sig(i1[e]); og = sig(o1[e]); ch = tanh_s(g1[e]);
        cn = fmaf(fg, c1[e], ig * ch);
        c1[e] = cn;
        hq[2 + e] = og * tanh_s(cn);
      }
      // scalar: j = sj
      fg = sig(fs); ig = sig(is); og = sig(os); ch = tanh_s(gs);
      cn = fmaf(fg, cs, ig * ch);
      cs = cn;
      hq[4] = og * tanh_s(cn);
    }

    hw[pb]     = hq[0];
    hw[pb + 1] = hq[1];
    hw[pb + 2] = hq[2];
    hw[pb + 3] = hq[3];
    hw[sj]     = hq[4];

    // out stores: two 8B + one 4B (t*80 + pb*4 is 8B-aligned)
    float* op = ob + t * H;
    *(f32x2*)(op + pb)     = f32x2{hq[0], hq[1]};
    *(f32x2*)(op + pb + 2) = f32x2{hq[2], hq[3]};
    op[sj] = hq[4];

    __syncthreads();   // hbuf[cur^1] visible before next t reads
    cur ^= 1;
  }
}

} // namespace

extern "C" void kernel_launch(void* const* d_in, const int* in_sizes, int n_in,
                              void* d_out, int out_size, void* d_ws, size_t ws_size,
                              hipStream_t stream) {
  const float* x  = (const float*)d_in[0];
  const float* wf = (const float*)d_in[1];
  const float* wi = (const float*)d_in[2];
  const float* wo = (const float*)d_in[3];
  const float* wc = (const float*)d_in[4];
  const float* uf = (const float*)d_in[5];
  const float* ui = (const float*)d_in[6];
  const float* uo = (const float*)d_in[7];
  const float* uc = (const float*)d_in[8];
  const float* bf = (const float*)d_in[9];
  const float* bi = (const float*)d_in[10];
  const float* bo = (const float*)d_in[11];
  const float* bc = (const float*)d_in[12];
  float* out = (float*)d_out;

  dim3 block(256);
  dim3 grid(BATCH / BPB);   // 2048 blocks
  hipLaunchKernelGGL(lstm_pk, grid, block, 0, stream,
                     x, wf, wi, wo, wc, uf, ui, uo, uc, bf, bi, bo, bc, out);
}